// Round 1
// baseline (349.020 us; speedup 1.0000x reference)
//
#include <hip/hip_runtime.h>

// DisplaceChannel: B=32, C=384 (48 pos x 8 ch), H=W=64, K=3, SIGMA=0.5.
// out(y,x) = sum_dy gy[dy] * sum_dx gx[dx] * mask * inp(y+dy-oy, x+dx-ox)
// Separable Gaussian; displacement mask and conv zero-pad mask are separable
// per-dimension and uniform per plane (block).
// v2: 4x4 outputs per thread, 16B/lane vector loads+stores.
// v3: skip ALL input loads in fully-masked regions. Avg valid output fraction
//     over the 48 positions is ~31% ((1-|ox|/64)(1-|oy|/64)); v2 loaded the
//     whole plane anyway and multiplied by zero. Tile-level early-out (all
//     taps masked in x or y -> store zeros, no loads) + per-row early-out in
//     hrow cuts HBM input fetch from ~201 MB to ~85 MB (write 201 MB fixed).
//     Valid taps provably read in-plane/in-row addresses, so arithmetic for
//     nonzero outputs is bit-identical to v2.

constexpr int HH = 64;
constexpr int WW = 64;
constexpr int B_ = 32;
constexpr int C_ = 384;
constexpr int PLANES = B_ * C_;                    // 12288
constexpr long long NELEM = (long long)PLANES * HH * WW;

__global__ __launch_bounds__(256) void displace_conv_v3(
    const float* __restrict__ inp, const float* __restrict__ offset,
    float* __restrict__ out) {
  const int plane = blockIdx.x;                    // [0, 12288)
  const int c = plane % C_;
  const int pos = c >> 3;                          // 8 channels per position

  const float offx = offset[2 * pos + 0];
  const float offy = offset[2 * pos + 1];
  const float rx = rintf(offx);                    // matches jnp.round
  const float ry = rintf(offy);
  const int ox = (int)rx;
  const int oy = (int)ry;
  const float fx = offx - rx;
  const float fy = offy - ry;

  const int t = threadIdx.x;
  const int cg = t & 15;                           // column group: cols 4cg..4cg+3
  const int rg = t >> 4;                           // row group: rows 4rg..4rg+3
  const int x4 = cg << 2;
  const int y0 = rg << 2;

  // Valid tap window in output-grid coords (conv zero-pad + displacement).
  const int xlo = ox > 0 ? ox : 0;
  const int xhi = ox < 0 ? WW + ox : WW;
  const int ylo = oy > 0 ? oy : 0;
  const int yhi = oy < 0 ? HH + oy : HH;

  float* __restrict__ obase = out + (size_t)plane * (HH * WW);

  // Tile-level early-out: tap cols are x4-1..x4+4, tap rows y0-1..y0+4.
  // If every tap is masked in x OR in y, all 16 outputs are exactly 0 and
  // no input bytes are needed. This is what removes the HBM over-fetch.
  const bool anyx = (x4 + 4 >= xlo) && (x4 - 1 < xhi);
  const bool anyy = (y0 + 4 >= ylo) && (y0 - 1 < yhi);
  if (!(anyx && anyy)) {
    const float4 z = make_float4(0.f, 0.f, 0.f, 0.f);
#pragma unroll
    for (int i = 0; i < 4; ++i)
      *(float4*)(obase + (y0 + i) * WW + x4) = z;  // output must be written
    return;
  }

  // Separable Gaussian taps, normalized so (sum gx)*(sum gy) = full 3x3 sum.
  // Computed after the early-out so fully-skipped waves pay nothing.
  float gx0 = __expf(-2.f * (fx - 1.f) * (fx - 1.f));
  float gx1 = __expf(-2.f * fx * fx);
  float gx2 = __expf(-2.f * (fx + 1.f) * (fx + 1.f));
  const float sxi = 1.f / (gx0 + gx1 + gx2);
  gx0 *= sxi; gx1 *= sxi; gx2 *= sxi;

  float gy0 = __expf(-2.f * (fy - 1.f) * (fy - 1.f));
  float gy1 = __expf(-2.f * fy * fy);
  float gy2 = __expf(-2.f * (fy + 1.f) * (fy + 1.f));
  const float syi = 1.f / (gy0 + gy1 + gy2);
  gy0 *= syi; gy1 *= syi; gy2 *= syi;

  // Six tap columns xt = x4-1+m (m=0..5); source col = xt-ox = q+m.
  const int q = x4 - 1 - ox;
  float vm[6];
#pragma unroll
  for (int m = 0; m < 6; ++m) {
    const int xt = x4 - 1 + m;
    vm[m] = (xt >= xlo && xt < xhi) ? 1.f : 0.f;
  }

  const float* __restrict__ pbase = inp + (size_t)plane * (HH * WW);
  const float* const lo = inp;
  const float* const hi = inp + (NELEM - 8);

  // Horizontal pass producing one tmp row (4 cols) for tap row ty.
  // Masked rows return zeros WITHOUT loading (exec-masked lanes issue no
  // VMEM requests -> those cache lines are never fetched from HBM).
  auto hrow = [&](int ty) -> float4 {
    if (ty < ylo || ty >= yhi)
      return make_float4(0.f, 0.f, 0.f, 0.f);
    const int tsrc = ty - oy;                      // in [0,63] when row valid
    const float* p = pbase + tsrc * WW + q;
    // Safety clamp into the buffer; never triggers for this input's offsets
    // (extreme |o| positions live at non-extreme plane indices). Valid taps
    // (vm!=0) always have 0 <= q+m < 64, so the clamp cannot skew them.
    p = p < lo ? lo : (p > hi ? hi : p);
    float s[8];
    __builtin_memcpy(&s[0], p, 16);                // align-4 dwordx4 loads
    __builtin_memcpy(&s[4], p + 4, 16);
#pragma unroll
    for (int m = 0; m < 6; ++m) s[m] *= vm[m];     // fold column masks in
    float4 r;
    r.x = gx0 * s[0] + gx1 * s[1] + gx2 * s[2];
    r.y = gx0 * s[1] + gx1 * s[2] + gx2 * s[3];
    r.z = gx0 * s[2] + gx1 * s[3] + gx2 * s[4];
    r.w = gx0 * s[3] + gx1 * s[4] + gx2 * s[5];
    return r;
  };

  // Vertical 3-tap sliding window over 6 tmp rows -> 4 output rows.
  float4 a = hrow(y0 - 1);
  float4 b = hrow(y0);
#pragma unroll
  for (int i = 0; i < 4; ++i) {
    const float4 cc = hrow(y0 + 1 + i);
    float4 o;
    o.x = gy0 * a.x + gy1 * b.x + gy2 * cc.x;
    o.y = gy0 * a.y + gy1 * b.y + gy2 * cc.y;
    o.z = gy0 * a.z + gy1 * b.z + gy2 * cc.z;
    o.w = gy0 * a.w + gy1 * b.w + gy2 * cc.w;
    *(float4*)(obase + (y0 + i) * WW + x4) = o;    // aligned 16B store
    a = b;
    b = cc;
  }
}

extern "C" void kernel_launch(void* const* d_in, const int* in_sizes, int n_in,
                              void* d_out, int out_size, void* d_ws, size_t ws_size,
                              hipStream_t stream) {
  const float* inp = (const float*)d_in[0];
  const float* offset = (const float*)d_in[1];
  float* out = (float*)d_out;
  displace_conv_v3<<<PLANES, 256, 0, stream>>>(inp, offset, out);
}

// Round 2
// 348.925 us; speedup vs baseline: 1.0003x; 1.0003x over previous
//
#include <hip/hip_runtime.h>

// DisplaceChannel: B=32, C=384 (48 pos x 8 ch), H=W=64, K=3, SIGMA=0.5.
// out(y,x) = sum_dy gy[dy] * sum_dx gx[dx] * mask * inp(y+dy-oy, x+dx-ox)
// Separable Gaussian; masks separable per-dimension, uniform per plane.
// v2: 4x4 outputs/thread, 16B/lane vector loads+stores (~72us kernel).
// v3 (REVERTED): per-row branch inside hrow regressed ~15-20us — divergent
//     if/else in the 6x-called lambda perturbed the straight-line codegen.
// v4: v2's exact branchless main path, plus
//     (a) tile-level early-out ONLY: a 4x4 tile whose whole 6x6 tap window
//         is masked stores exact zeros and issues no loads. Branch sits
//         before any loads; main path codegen is untouched. Cuts input
//         fetch ~201 MB -> ~105 MB (avg valid fraction ~0.33 + halo ring).
//         Row-clamped taps on surviving tiles only re-read source rows
//         0/63, which the valid region fetches anyway.
//     (b) nontemporal stores for all output: output is write-once and
//         never re-read; 201 MB of streaming writes otherwise evict the
//         input lines (in+out > 256 MB L3) being read concurrently.

constexpr int HH = 64;
constexpr int WW = 64;
constexpr int B_ = 32;
constexpr int C_ = 384;
constexpr int PLANES = B_ * C_;                    // 12288
constexpr long long NELEM = (long long)PLANES * HH * WW;

typedef float f32x4 __attribute__((ext_vector_type(4)));

__global__ __launch_bounds__(256) void displace_conv_v4(
    const float* __restrict__ inp, const float* __restrict__ offset,
    float* __restrict__ out) {
  const int plane = blockIdx.x;                    // [0, 12288)
  const int c = plane % C_;
  const int pos = c >> 3;                          // 8 channels per position

  const float offx = offset[2 * pos + 0];
  const float offy = offset[2 * pos + 1];
  const float rx = rintf(offx);                    // matches jnp.round
  const float ry = rintf(offy);
  const int ox = (int)rx;
  const int oy = (int)ry;
  const float fx = offx - rx;
  const float fy = offy - ry;

  const int t = threadIdx.x;
  const int cg = t & 15;                           // column group: cols 4cg..4cg+3
  const int rg = t >> 4;                           // row group: rows 4rg..4rg+3
  const int x4 = cg << 2;
  const int y0 = rg << 2;

  // Valid tap window in output-grid coords (conv zero-pad + displacement).
  const int xlo = ox > 0 ? ox : 0;
  const int xhi = ox < 0 ? WW + ox : WW;
  const int ylo = oy > 0 ? oy : 0;
  const int yhi = oy < 0 ? HH + oy : HH;

  float* __restrict__ obase = out + (size_t)plane * (HH * WW);

  // Tile-level early-out: tap cols x4-1..x4+4, tap rows y0-1..y0+4. If every
  // tap is masked in x OR y, all 16 outputs are exactly 0; store and leave
  // without touching the input. This is the only branch added over v2.
  const bool anyx = (x4 + 4 >= xlo) && (x4 - 1 < xhi);
  const bool anyy = (y0 + 4 >= ylo) && (y0 - 1 < yhi);
  if (!(anyx && anyy)) {
    const f32x4 z = {0.f, 0.f, 0.f, 0.f};
#pragma unroll
    for (int i = 0; i < 4; ++i)
      __builtin_nontemporal_store(z, (f32x4*)(obase + (y0 + i) * WW + x4));
    return;
  }

  // Separable Gaussian taps, normalized so (sum gx)*(sum gy) = full 3x3 sum.
  float gx0 = __expf(-2.f * (fx - 1.f) * (fx - 1.f));
  float gx1 = __expf(-2.f * fx * fx);
  float gx2 = __expf(-2.f * (fx + 1.f) * (fx + 1.f));
  const float sxi = 1.f / (gx0 + gx1 + gx2);
  gx0 *= sxi; gx1 *= sxi; gx2 *= sxi;

  float gy0 = __expf(-2.f * (fy - 1.f) * (fy - 1.f));
  float gy1 = __expf(-2.f * fy * fy);
  float gy2 = __expf(-2.f * (fy + 1.f) * (fy + 1.f));
  const float syi = 1.f / (gy0 + gy1 + gy2);
  gy0 *= syi; gy1 *= syi; gy2 *= syi;

  // Six tap columns xt = x4-1+m (m=0..5); source col = xt-ox = q+m.
  const int q = x4 - 1 - ox;
  float vm[6];
#pragma unroll
  for (int m = 0; m < 6; ++m) {
    const int xt = x4 - 1 + m;
    vm[m] = (xt >= xlo && xt < xhi) ? 1.f : 0.f;
  }

  const float* __restrict__ pbase = inp + (size_t)plane * (HH * WW);
  const float* const lo = inp;
  const float* const hi = inp + (NELEM - 8);

  // Horizontal pass producing one tmp row (4 cols) for tap row ty.
  // Branchless (v2 codegen): masked rows use rs=0 with clamped source row;
  // on surviving tiles the clamp only re-touches rows 0/63, already fetched.
  auto hrow = [&](int ty) -> f32x4 {
    const float rs = (ty >= ylo && ty < yhi) ? 1.f : 0.f;
    int tsrc = ty - oy;
    tsrc = tsrc < 0 ? 0 : (tsrc > HH - 1 ? HH - 1 : tsrc);
    const float* p = pbase + tsrc * WW + q;
    // Safety clamp into the buffer; never triggers for this input's offsets.
    p = p < lo ? lo : (p > hi ? hi : p);
    float s[8];
    __builtin_memcpy(&s[0], p, 16);                // align-4 dwordx4 loads
    __builtin_memcpy(&s[4], p + 4, 16);
#pragma unroll
    for (int m = 0; m < 6; ++m) s[m] *= vm[m];     // fold column masks in
    f32x4 r;
    r.x = rs * (gx0 * s[0] + gx1 * s[1] + gx2 * s[2]);
    r.y = rs * (gx0 * s[1] + gx1 * s[2] + gx2 * s[3]);
    r.z = rs * (gx0 * s[2] + gx1 * s[3] + gx2 * s[4]);
    r.w = rs * (gx0 * s[3] + gx1 * s[4] + gx2 * s[5]);
    return r;
  };

  // Vertical 3-tap sliding window over 6 tmp rows -> 4 output rows.
  f32x4 a = hrow(y0 - 1);
  f32x4 b = hrow(y0);
#pragma unroll
  for (int i = 0; i < 4; ++i) {
    const f32x4 cc = hrow(y0 + 1 + i);
    f32x4 o;
    o.x = gy0 * a.x + gy1 * b.x + gy2 * cc.x;
    o.y = gy0 * a.y + gy1 * b.y + gy2 * cc.y;
    o.z = gy0 * a.z + gy1 * b.z + gy2 * cc.z;
    o.w = gy0 * a.w + gy1 * b.w + gy2 * cc.w;
    __builtin_nontemporal_store(o, (f32x4*)(obase + (y0 + i) * WW + x4));
    a = b;
    b = cc;
  }
}

extern "C" void kernel_launch(void* const* d_in, const int* in_sizes, int n_in,
                              void* d_out, int out_size, void* d_ws, size_t ws_size,
                              hipStream_t stream) {
  const float* inp = (const float*)d_in[0];
  const float* offset = (const float*)d_in[1];
  float* out = (float*)d_out;
  displace_conv_v4<<<PLANES, 256, 0, stream>>>(inp, offset, out);
}

// Round 3
// 322.604 us; speedup vs baseline: 1.0819x; 1.0816x over previous
//
#include <hip/hip_runtime.h>

// DisplaceChannel: B=32, C=384 (48 pos x 8 ch), H=W=64, K=3, SIGMA=0.5.
// out(y,x) = sum_dy gy[dy] * sum_dx gx[dx] * mask * inp(y+dy-oy, x+dx-ox)
// Separable Gaussian; masks separable per-dimension, uniform per plane.
// v2: 4x4 outputs/thread, 16B/lane vector loads+stores (~74us kernel).
// v3 (REVERTED): per-row branch in hrow + 4x4 early-out: +30us.
// v4 (REVERTED): branchless + 4x4 early-out + NT stores: also +30us.
//     -> either NT stores (L2-bypass write BW) or the per-lane 4x4 skip
//        (partial-128B-line store instructions at 16-aligned x boundaries
//        -> L2 write-allocate RMW) is the regression.
// v5: v2 main path + PLAIN stores (no NT) + LINE-SAFE early-out:
//     skip granularity 32 cols (one 128B output line) x 4 rows. The x-skip
//     decision is uniform per 8-lane half-row-group and y-skip uniform per
//     16-lane row-group, so every store instruction writes whole 128B
//     lines — divergence can no longer fragment lines. Skip is exact:
//     offsets round to multiples of 16, tap window [xg-1,xg+32]x[y0-1,y0+4]
//     disjoint from valid window => all 16 outputs identically 0.
//     Expected fetch 201 MB -> ~110 MB.

constexpr int HH = 64;
constexpr int WW = 64;
constexpr int B_ = 32;
constexpr int C_ = 384;
constexpr int PLANES = B_ * C_;                    // 12288
constexpr long long NELEM = (long long)PLANES * HH * WW;

typedef float f32x4 __attribute__((ext_vector_type(4)));

__global__ __launch_bounds__(256) void displace_conv_v5(
    const float* __restrict__ inp, const float* __restrict__ offset,
    float* __restrict__ out) {
  const int plane = blockIdx.x;                    // [0, 12288)
  const int c = plane % C_;
  const int pos = c >> 3;                          // 8 channels per position

  const float offx = offset[2 * pos + 0];
  const float offy = offset[2 * pos + 1];
  const float rx = rintf(offx);                    // matches jnp.round
  const float ry = rintf(offy);
  const int ox = (int)rx;
  const int oy = (int)ry;
  const float fx = offx - rx;
  const float fy = offy - ry;

  const int t = threadIdx.x;
  const int cg = t & 15;                           // column group: cols 4cg..4cg+3
  const int rg = t >> 4;                           // row group: rows 4rg..4rg+3
  const int x4 = cg << 2;
  const int y0 = rg << 2;

  // Valid tap window in output-grid coords (conv zero-pad + displacement).
  const int xlo = ox > 0 ? ox : 0;
  const int xhi = ox < 0 ? WW + ox : WW;
  const int ylo = oy > 0 ? oy : 0;
  const int yhi = oy < 0 ? HH + oy : HH;

  float* __restrict__ obase = out + (size_t)plane * (HH * WW);

  // Line-safe early-out. x at 32-col (one 128B line) granularity: the
  // 32-col group's tap cols are [xg-1, xg+32]; y at the lane's own 4-row
  // tile: tap rows [y0-1, y0+4]. If either range misses the valid window,
  // all 16 outputs of this lane are exactly 0 and no input is needed.
  // Store-instruction line integrity: y-decision uniform over each 16-lane
  // row-group; x-decision uniform over each 8-lane (128B) half — so both
  // the zero path's and the main path's store instructions always cover
  // whole 128B output lines.
  const int xg = x4 & ~31;                         // 0 or 32
  const bool runx = (xg + 32 >= xlo) && (xg - 1 < xhi);
  const bool runy = (y0 + 4 >= ylo) && (y0 - 1 < yhi);
  if (!(runx && runy)) {
    const f32x4 z = {0.f, 0.f, 0.f, 0.f};
#pragma unroll
    for (int i = 0; i < 4; ++i)
      *(f32x4*)(obase + (y0 + i) * WW + x4) = z;   // output must be written
    return;
  }

  // Separable Gaussian taps, normalized so (sum gx)*(sum gy) = full 3x3 sum.
  float gx0 = __expf(-2.f * (fx - 1.f) * (fx - 1.f));
  float gx1 = __expf(-2.f * fx * fx);
  float gx2 = __expf(-2.f * (fx + 1.f) * (fx + 1.f));
  const float sxi = 1.f / (gx0 + gx1 + gx2);
  gx0 *= sxi; gx1 *= sxi; gx2 *= sxi;

  float gy0 = __expf(-2.f * (fy - 1.f) * (fy - 1.f));
  float gy1 = __expf(-2.f * fy * fy);
  float gy2 = __expf(-2.f * (fy + 1.f) * (fy + 1.f));
  const float syi = 1.f / (gy0 + gy1 + gy2);
  gy0 *= syi; gy1 *= syi; gy2 *= syi;

  // Six tap columns xt = x4-1+m (m=0..5); source col = xt-ox = q+m.
  const int q = x4 - 1 - ox;
  float vm[6];
#pragma unroll
  for (int m = 0; m < 6; ++m) {
    const int xt = x4 - 1 + m;
    vm[m] = (xt >= xlo && xt < xhi) ? 1.f : 0.f;
  }

  const float* __restrict__ pbase = inp + (size_t)plane * (HH * WW);
  const float* const lo = inp;
  const float* const hi = inp + (NELEM - 8);

  // Horizontal pass producing one tmp row (4 cols) for tap row ty.
  // Branchless (exact v2 codegen): masked rows use rs=0 with clamped source
  // row; on surviving tiles the clamp only re-touches rows 0/63, which the
  // valid region fetches anyway.
  auto hrow = [&](int ty) -> f32x4 {
    const float rs = (ty >= ylo && ty < yhi) ? 1.f : 0.f;
    int tsrc = ty - oy;
    tsrc = tsrc < 0 ? 0 : (tsrc > HH - 1 ? HH - 1 : tsrc);
    const float* p = pbase + tsrc * WW + q;
    // Safety clamp into the buffer; never triggers for this input's offsets.
    p = p < lo ? lo : (p > hi ? hi : p);
    float s[8];
    __builtin_memcpy(&s[0], p, 16);                // align-4 dwordx4 loads
    __builtin_memcpy(&s[4], p + 4, 16);
#pragma unroll
    for (int m = 0; m < 6; ++m) s[m] *= vm[m];     // fold column masks in
    f32x4 r;
    r.x = rs * (gx0 * s[0] + gx1 * s[1] + gx2 * s[2]);
    r.y = rs * (gx0 * s[1] + gx1 * s[2] + gx2 * s[3]);
    r.z = rs * (gx0 * s[2] + gx1 * s[3] + gx2 * s[4]);
    r.w = rs * (gx0 * s[3] + gx1 * s[4] + gx2 * s[5]);
    return r;
  };

  // Vertical 3-tap sliding window over 6 tmp rows -> 4 output rows.
  f32x4 a = hrow(y0 - 1);
  f32x4 b = hrow(y0);
#pragma unroll
  for (int i = 0; i < 4; ++i) {
    const f32x4 cc = hrow(y0 + 1 + i);
    f32x4 o;
    o.x = gy0 * a.x + gy1 * b.x + gy2 * cc.x;
    o.y = gy0 * a.y + gy1 * b.y + gy2 * cc.y;
    o.z = gy0 * a.z + gy1 * b.z + gy2 * cc.z;
    o.w = gy0 * a.w + gy1 * b.w + gy2 * cc.w;
    *(f32x4*)(obase + (y0 + i) * WW + x4) = o;     // aligned 16B store
    a = b;
    b = cc;
  }
}

extern "C" void kernel_launch(void* const* d_in, const int* in_sizes, int n_in,
                              void* d_out, int out_size, void* d_ws, size_t ws_size,
                              hipStream_t stream) {
  const float* inp = (const float*)d_in[0];
  const float* offset = (const float*)d_in[1];
  float* out = (float*)d_out;
  displace_conv_v5<<<PLANES, 256, 0, stream>>>(inp, offset, out);
}